// Round 16
// baseline (228.289 us; speedup 1.0000x reference)
//
#include <hip/hip_runtime.h>

// B=8, T=8, S=500 (padded 512), F_IN=32, F=F_OUT=64, K=3, L=3
#define BB 8
#define TT 8
#define SS 500
#define SP 512
#define FIN 32
#define FF 64
#define NBT 64
#define KT 1536        // 24 * 64 : tmix GEMM K  (k = t'*192 + b'*64 + j)
#define LROW_S 264     // smm LDS row stride in shorts (BK=256 + 8 pad)
#define LROW_T 520     // tmix LDS row stride in shorts (BK=512 + 8 pad)

typedef short bf16x8 __attribute__((ext_vector_type(8)));
typedef float floatx4 __attribute__((ext_vector_type(4)));

__device__ __forceinline__ unsigned f2bf(float x) {
    unsigned u = __builtin_bit_cast(unsigned, x);
    return (u + 0x7FFFu + ((u >> 16) & 1u)) >> 16;   // RNE bf16 in low 16
}
__device__ __forceinline__ float bf2f(unsigned short h) {
    unsigned u = ((unsigned)h) << 16;
    return __builtin_bit_cast(float, u);
}

__device__ __forceinline__ void ctab(int m, float s0, float s1, float s2, float s3,
                                     float& c0, float& c1, float& c2) {
    c0 = 0.f; c1 = 0.f; c2 = 0.f;
    switch (m) {
        case 0: c0 = 1.f; c1 = s0; c2 = s0 * s0; break;
        case 1: c1 = s1; c2 = 2.f * s0 * s1; break;
        case 2: c2 = s1 * s1; break;
        case 3: c1 = s2; c2 = 2.f * s0 * s2; break;
        case 4: c1 = s3; c2 = 2.f * (s0 * s3 + s1 * s2); break;
        case 5: c2 = 2.f * s1 * s3; break;
        case 6: c2 = s2 * s2; break;
        case 7: c2 = 2.f * s2 * s3; break;
        case 8: c2 = s3 * s3; break;
    }
}

// ---------------------------------------------------------------------------
// setup_k (exact R12): blocks [0,512): lin1; blocks [512,...): Asb/AsbT + GbigT
// ---------------------------------------------------------------------------
__global__ __launch_bounds__(256) void setup_k(const float* __restrict__ x,
                                               const float* __restrict__ W1,
                                               const float* __restrict__ b1,
                                               const float* __restrict__ As,
                                               const float* __restrict__ At,
                                               const float* __restrict__ sc,
                                               const float* __restrict__ H,
                                               unsigned short* __restrict__ Asb,
                                               unsigned short* __restrict__ AsbT,
                                               unsigned short* __restrict__ GbigT,
                                               unsigned short* __restrict__ xfT,
                                               unsigned short* __restrict__ Abig0) {
    int tid = threadIdx.x;
    if (blockIdx.x < 512) {
        // ---- lin1 path
        __shared__ float Xs[64][FIN + 1];
        __shared__ float Wl[FIN][FF];
        __shared__ float Ot[64][FF + 1];
        __shared__ float bl[FF];
        int bt = blockIdx.x >> 3, s0 = (blockIdx.x & 7) * 64;
        int b = bt >> 3, t = bt & 7;

        for (int i = tid; i < FIN * FF; i += 256) { int f = i >> 5, j = i & 31; Wl[j][f] = W1[i]; }
        if (tid < FF) bl[tid] = b1[tid];
        const float* xb = x + (size_t)bt * SS * FIN;
        #pragma unroll
        for (int i = 0; i < 8; ++i) {
            int lin = i * 256 + tid; int r = lin >> 5, j = lin & 31;
            int s = s0 + r;
            Xs[r][j] = (s < SS) ? xb[(size_t)s * FIN + j] : 0.f;
        }
        __syncthreads();
        int f = tid & 63, sq = tid >> 6;
        for (int i = 0; i < 16; ++i) {
            int r = sq * 16 + i;
            float acc = bl[f];
            #pragma unroll
            for (int j = 0; j < FIN; ++j) acc += Xs[r][j] * Wl[j][f];
            Ot[r][f] = (s0 + r < SS) ? acc : 0.f;
        }
        __syncthreads();
        // Abig0 slot0 write (row-major)
        #pragma unroll
        for (int it = 0; it < 2; ++it) {
            int idx = it * 256 + tid;
            int row = idx >> 3, c = idx & 7;
            int4 w;
            unsigned short tmp[8];
            #pragma unroll
            for (int q = 0; q < 8; ++q) tmp[q] = (unsigned short)f2bf(Ot[row][c * 8 + q]);
            w.x = tmp[0] | (tmp[1] << 16); w.y = tmp[2] | (tmp[3] << 16);
            w.z = tmp[4] | (tmp[5] << 16); w.w = tmp[6] | (tmp[7] << 16);
            *(int4*)(Abig0 + (size_t)(b * SP + s0 + row) * KT + t * 192 + c * 8) = w;
        }
        // transposed write
        {
            int ff = tid >> 2, scol = (tid & 3) * 16;
            unsigned short tmp[16];
            #pragma unroll
            for (int i = 0; i < 16; ++i) tmp[i] = (unsigned short)f2bf(Ot[scol + i][ff]);
            unsigned short* dp = xfT + ((size_t)bt * FF + ff) * SP + s0 + scol;
            #pragma unroll
            for (int q = 0; q < 2; ++q) {
                int4 w;
                w.x = tmp[q*8+0] | (tmp[q*8+1] << 16); w.y = tmp[q*8+2] | (tmp[q*8+3] << 16);
                w.z = tmp[q*8+4] | (tmp[q*8+5] << 16); w.w = tmp[q*8+6] | (tmp[q*8+7] << 16);
                *(int4*)(dp + q * 8) = w;
            }
        }
        return;
    }
    // ---- prep path
    int idx = (blockIdx.x - 512) * 256 + tid;
    if (idx < 262144) {
        int s = idx >> 9, k = idx & 511;
        Asb[idx] = (s < SS && k < SS) ? (unsigned short)f2bf(As[(size_t)s * SS + k]) : 0;
    } else if (idx < 524288) {
        int r = idx - 262144;
        int j = r >> 9, k = r & 511;
        AsbT[r] = (j < SS && k < SS) ? (unsigned short)f2bf(As[(size_t)k * SS + j]) : 0;
    } else {
        int r = idx - 524288;                 // [0, 3*8*64*1536)
        if (r < 2359296) {
            int l = r / 786432;
            int r2 = r - l * 786432;
            int t = r2 / 98304;
            int r3 = r2 - t * 98304;
            int f = r3 / 1536;
            int k = r3 - f * 1536;            // 1536 not pow2 — subtract, not AND
            int seg = k >> 6, j = k & 63;
            int tp = seg / 3, bp = seg - tp * 3;

            float s0 = sc[0], s1 = sc[1], s2 = sc[2], s3 = sc[3];
            float w0 = (t == tp) ? 1.f : 0.f;
            float w1 = At[t * 8 + tp];
            float w2 = 0.f;
            #pragma unroll
            for (int kk = 0; kk < 8; ++kk) w2 += At[t * 8 + kk] * At[kk * 8 + tp];

            float a0, a1, a2, b0, b1, b2, d0, d1, d2;
            ctab(0 * 3 + bp, s0, s1, s2, s3, a0, a1, a2);
            ctab(1 * 3 + bp, s0, s1, s2, s3, b0, b1, b2);
            ctab(2 * 3 + bp, s0, s1, s2, s3, d0, d1, d2);
            float k0c = w0 * a0 + w1 * b0 + w2 * d0;
            float k1c = w0 * a1 + w1 * b1 + w2 * d1;
            float k2c = w0 * a2 + w1 * b2 + w2 * d2;

            float val = k0c * H[((size_t)(l * 3 + 0) * 64 + j) * 64 + f]
                      + k1c * H[((size_t)(l * 3 + 1) * 64 + j) * 64 + f]
                      + k2c * H[((size_t)(l * 3 + 2) * 64 + j) * 64 + f];
            GbigT[r] = (unsigned short)f2bf(val);
        }
    }
}

// ---------------------------------------------------------------------------
// prep2 (exact R12): Asqb = (As@As) bf16 [512][512]
// ---------------------------------------------------------------------------
__global__ __launch_bounds__(256) void prep2_k(const unsigned short* __restrict__ Asb,
                                               const unsigned short* __restrict__ AsbT,
                                               unsigned short* __restrict__ Asqb) {
    int tid = threadIdx.x;
    int wave = tid >> 6, lane = tid & 63;
    int l16 = lane & 15, quad = lane >> 4;
    int st = blockIdx.x, ct = blockIdx.y;

    const unsigned short* ap = Asb + (size_t)(st * 16 + l16) * SP + quad * 8;
    const unsigned short* bp = AsbT + (size_t)(ct * 64 + wave * 16 + l16) * SP + quad * 8;
    floatx4 acc = {};
    #pragma unroll 4
    for (int k0 = 0; k0 < SP; k0 += 32)
        acc = __builtin_amdgcn_mfma_f32_16x16x32_bf16(*(const bf16x8*)(ap + k0),
                                                      *(const bf16x8*)(bp + k0), acc, 0, 0, 0);
    int j = ct * 64 + wave * 16 + l16;
    int i0 = st * 16 + quad * 4;
    #pragma unroll
    for (int r = 0; r < 4; ++r)
        Asqb[(size_t)(i0 + r) * SP + j] = (unsigned short)f2bf(acc[r]);
}

// ---------------------------------------------------------------------------
// smm (BK=256, 2 k-steps): u1 = As.xf, u2 = As^2.xf -> Abig slots 1,2.
// grid (8 m-tiles, 64 bt). LDS 3 x 64 x 264 shorts = 101 KB.
// ---------------------------------------------------------------------------
__global__ __launch_bounds__(256) void smm_k(const unsigned short* __restrict__ Asb,
                                             const unsigned short* __restrict__ Asqb,
                                             const unsigned short* __restrict__ xfT,
                                             unsigned short* __restrict__ Abig) {
    __shared__ unsigned short A1[64 * LROW_S];
    __shared__ unsigned short A2[64 * LROW_S];
    __shared__ unsigned short Bt[64 * LROW_S];

    int tid = threadIdx.x;
    int wave = tid >> 6, lane = tid & 63;
    int l16 = lane & 15, quad = lane >> 4;
    int m0 = blockIdx.x * 64, bt = blockIdx.y;
    int b = bt >> 3, t = bt & 7;

    const unsigned short* a1g = Asb + (size_t)m0 * SP;
    const unsigned short* a2g = Asqb + (size_t)m0 * SP;
    const unsigned short* bg  = xfT + (size_t)bt * FF * SP;

    floatx4 acc1[4] = {}, acc2[4] = {};

    for (int k0 = 0; k0 < SP; k0 += 256) {
        __syncthreads();
        // stage: each mat 64 rows x 32 int4 (256 shorts); 8 int4/thread/mat
        #pragma unroll
        for (int it = 0; it < 8; ++it) {
            int idx = it * 256 + tid;
            int row = idx >> 5, c = idx & 31;
            int4 v1 = *(const int4*)(a1g + (size_t)row * SP + k0 + c * 8);
            int4 v2 = *(const int4*)(a2g + (size_t)row * SP + k0 + c * 8);
            int4 vb = *(const int4*)(bg  + (size_t)row * SP + k0 + c * 8);
            *(int4*)&A1[row * LROW_S + c * 8] = v1;
            *(int4*)&A2[row * LROW_S + c * 8] = v2;
            *(int4*)&Bt[row * LROW_S + c * 8] = vb;
        }
        __syncthreads();
        #pragma unroll
        for (int ks = 0; ks < 8; ++ks) {
            bf16x8 af1 = *(const bf16x8*)&A1[(wave * 16 + l16) * LROW_S + ks * 32 + quad * 8];
            bf16x8 af2 = *(const bf16x8*)&A2[(wave * 16 + l16) * LROW_S + ks * 32 + quad * 8];
            #pragma unroll
            for (int nt = 0; nt < 4; ++nt) {
                bf16x8 bf = *(const bf16x8*)&Bt[(nt * 16 + l16) * LROW_S + ks * 32 + quad * 8];
                acc1[nt] = __builtin_amdgcn_mfma_f32_16x16x32_bf16(af1, bf, acc1[nt], 0, 0, 0);
                acc2[nt] = __builtin_amdgcn_mfma_f32_16x16x32_bf16(af2, bf, acc2[nt], 0, 0, 0);
            }
        }
    }

    // epilogue: repack to row-major via LDS, write Abig slots 1 and 2
    __syncthreads();
    #pragma unroll
    for (int nt = 0; nt < 4; ++nt)
        #pragma unroll
        for (int r = 0; r < 4; ++r) {
            A1[(wave * 16 + quad * 4 + r) * LROW_S + nt * 16 + l16] = (unsigned short)f2bf(acc1[nt][r]);
            A2[(wave * 16 + quad * 4 + r) * LROW_S + nt * 16 + l16] = (unsigned short)f2bf(acc2[nt][r]);
        }
    __syncthreads();
    int row = wave * 16 + (lane >> 2);
    int c2 = (lane & 3) * 2;
    #pragma unroll
    for (int q = 0; q < 2; ++q) {
        int c = c2 + q;
        int4 v1 = *(const int4*)&A1[row * LROW_S + c * 8];
        int4 v2 = *(const int4*)&A2[row * LROW_S + c * 8];
        size_t base = (size_t)(b * SP + m0 + row) * KT + t * 192;
        *(int4*)(Abig + base + 64 + c * 8)  = v1;
        *(int4*)(Abig + base + 128 + c * 8) = v2;
    }
}

// ---------------------------------------------------------------------------
// tmix (BK=512, 3 k-steps, 2x2 wave tiles): grid (64 m-tiles, 8 t).
// C[(b,s)][(t,f)] = tanh( Abig @ GbigT_l[t]^T ). LDS 2 x 64 x 520 shorts = 133 KB.
// Writes xfT_next (if wflag) + Abig_next slot0.
// ---------------------------------------------------------------------------
__global__ __launch_bounds__(256) void tmix_k(const unsigned short* __restrict__ Abig,
                                              const unsigned short* __restrict__ GbigT_l,
                                              unsigned short* __restrict__ xfT_out,
                                              unsigned short* __restrict__ Abig_out,
                                              int wflag) {
    __shared__ unsigned short At_[64 * LROW_T];
    __shared__ unsigned short Bt_[64 * LROW_T];

    int tid = threadIdx.x;
    int wave = tid >> 6, lane = tid & 63;
    int l16 = lane & 15, quad = lane >> 4;
    int mi = wave & 1, ni = wave >> 1;     // 2x2 wave grid over 64x64 tile
    int m0 = blockIdx.x * 64, t = blockIdx.y;
    int b = m0 >> 9, s0 = m0 & 511;

    const unsigned short* ag = Abig + (size_t)m0 * KT;
    const unsigned short* bg = GbigT_l + (size_t)t * FF * KT;

    floatx4 acc[2][2] = {};

    for (int kk = 0; kk < 3; ++kk) {
        __syncthreads();
        // stage: each mat 64 rows x 64 int4 (512 shorts); 16 int4/thread/mat
        #pragma unroll
        for (int it = 0; it < 16; ++it) {
            int idx = it * 256 + tid;
            int row = idx >> 6, c = idx & 63;
            int4 va = *(const int4*)(ag + (size_t)row * KT + kk * 512 + c * 8);
            int4 vb = *(const int4*)(bg + (size_t)row * KT + kk * 512 + c * 8);
            *(int4*)&At_[row * LROW_T + c * 8] = va;
            *(int4*)&Bt_[row * LROW_T + c * 8] = vb;
        }
        __syncthreads();
        #pragma unroll
        for (int ks = 0; ks < 16; ++ks) {
            bf16x8 af[2], bf[2];
            #pragma unroll
            for (int mt = 0; mt < 2; ++mt)
                af[mt] = *(const bf16x8*)&At_[(mi * 32 + mt * 16 + l16) * LROW_T + ks * 32 + quad * 8];
            #pragma unroll
            for (int nt = 0; nt < 2; ++nt)
                bf[nt] = *(const bf16x8*)&Bt_[(ni * 32 + nt * 16 + l16) * LROW_T + ks * 32 + quad * 8];
            #pragma unroll
            for (int mt = 0; mt < 2; ++mt)
                #pragma unroll
                for (int nt = 0; nt < 2; ++nt)
                    acc[mt][nt] = __builtin_amdgcn_mfma_f32_16x16x32_bf16(af[mt], bf[nt], acc[mt][nt], 0, 0, 0);
        }
    }

    // tanh
    #pragma unroll
    for (int mt = 0; mt < 2; ++mt)
        #pragma unroll
        for (int nt = 0; nt < 2; ++nt)
            #pragma unroll
            for (int r = 0; r < 4; ++r) acc[mt][nt][r] = tanhf(acc[mt][nt][r]);

    int bt = b * 8 + t;

    // xfT write straight from registers (skipped on last layer)
    if (wflag) {
        #pragma unroll
        for (int mt = 0; mt < 2; ++mt) {
            int sbase = s0 + mi * 32 + mt * 16 + quad * 4;
            #pragma unroll
            for (int nt = 0; nt < 2; ++nt) {
                int f = ni * 32 + nt * 16 + l16;
                int2 w;
                w.x = (int)(f2bf(acc[mt][nt][0]) | (f2bf(acc[mt][nt][1]) << 16));
                w.y = (int)(f2bf(acc[mt][nt][2]) | (f2bf(acc[mt][nt][3]) << 16));
                *(int2*)(xfT_out + ((size_t)bt * FF + f) * SP + sbase) = w;
            }
        }
    }

    // Abig_out slot0 via LDS repack (coalesced int4 rows)
    __syncthreads();
    #pragma unroll
    for (int mt = 0; mt < 2; ++mt)
        #pragma unroll
        for (int nt = 0; nt < 2; ++nt)
            #pragma unroll
            for (int r = 0; r < 4; ++r)
                At_[(mi * 32 + mt * 16 + quad * 4 + r) * LROW_T + ni * 32 + nt * 16 + l16] =
                    (unsigned short)f2bf(acc[mt][nt][r]);
    __syncthreads();
    {
        int row = wave * 16 + (lane >> 2);
        int c2 = (lane & 3) * 2;
        #pragma unroll
        for (int q = 0; q < 2; ++q) {
            int c = c2 + q;
            int4 v = *(const int4*)&At_[row * LROW_T + c * 8];
            *(int4*)(Abig_out + (size_t)(m0 + row) * KT + t * 192 + c * 8) = v;
        }
    }
}

// ---------------------------------------------------------------------------
// zredlin2 (exact R12): out[b,s,f] = b2[f]*sum(m) + z @ W2^T, z from Abig slot0.
// grid (32 s-tiles of 16, 8 b)
// ---------------------------------------------------------------------------
__global__ __launch_bounds__(256) void zredlin2_k(const unsigned short* __restrict__ Abig,
                                                  const float* __restrict__ W2,
                                                  const float* __restrict__ b2,
                                                  const float* __restrict__ merge,
                                                  float* __restrict__ out) {
    __shared__ float Wl[FF][FF + 1];
    __shared__ float zt[16][FF + 1];
    __shared__ float ml[TT];
    int tid = threadIdx.x;
    int b = blockIdx.y, s0 = blockIdx.x * 16;

    for (int i = tid; i < FF * FF; i += 256) { int f = i >> 6, j = i & 63; Wl[j][f] = W2[i]; }
    if (tid < TT) ml[tid] = merge[tid];
    __syncthreads();

    float m[TT];
    #pragma unroll
    for (int t = 0; t < TT; ++t) m[t] = ml[t];
    float msum = 0.f;
    #pragma unroll
    for (int t = 0; t < TT; ++t) msum += m[t];

    #pragma unroll
    for (int p = 0; p < 4; ++p) {
        int lin = p * 256 + tid;
        int sl = lin >> 6, f = lin & 63;
        int s = s0 + sl;
        float acc = 0.f;
        if (s < SS) {
            #pragma unroll
            for (int t = 0; t < TT; ++t)
                acc += m[t] * bf2f(Abig[(size_t)(b * SP + s) * KT + t * 192 + f]);
        }
        zt[sl][f] = acc;
    }
    __syncthreads();

    int f = tid & 63, sq = tid >> 6;
    #pragma unroll
    for (int i = 0; i < 4; ++i) {
        int sl = sq * 4 + i;
        int s = s0 + sl;
        if (s < SS) {
            float acc = b2[f] * msum;
            #pragma unroll
            for (int j = 0; j < FF; ++j) acc += zt[sl][j] * Wl[j][f];
            out[((size_t)b * SS + s) * FF + f] = acc;
        }
    }
}

// ---------------------------------------------------------------------------
extern "C" void kernel_launch(void* const* d_in, const int* in_sizes, int n_in,
                              void* d_out, int out_size, void* d_ws, size_t ws_size,
                              hipStream_t stream) {
    const float* x     = (const float*)d_in[0];
    const float* At    = (const float*)d_in[1];
    const float* As    = (const float*)d_in[2];
    const float* sc    = (const float*)d_in[3];
    const float* H     = (const float*)d_in[4];
    const float* W1    = (const float*)d_in[5];
    const float* b1    = (const float*)d_in[6];
    const float* W2    = (const float*)d_in[7];
    const float* b2    = (const float*)d_in[8];
    const float* merge = (const float*)d_in[9];
    float* out = (float*)d_out;

    char* ws = (char*)d_ws;
    unsigned short* Asb   = (unsigned short*)(ws + 0);          // 524288
    unsigned short* AsbT  = (unsigned short*)(ws + 524288);     // 524288
    unsigned short* Asqb  = (unsigned short*)(ws + 1048576);    // 524288
    unsigned short* GbigT = (unsigned short*)(ws + 1572864);    // 4718592
    unsigned short* xfT0  = (unsigned short*)(ws + 6291456);    // 4194304
    unsigned short* xfT1  = (unsigned short*)(ws + 10485760);   // 4194304
    unsigned short* Abig0 = (unsigned short*)(ws + 14680064);   // 12582912
    unsigned short* Abig1 = (unsigned short*)(ws + 27262976);   // 12582912

    setup_k<<<11776, 256, 0, stream>>>(x, W1, b1, As, At, sc, H,
                                       Asb, AsbT, GbigT, xfT0, Abig0);
    prep2_k<<<dim3(32, 8), 256, 0, stream>>>(Asb, AsbT, Asqb);

    unsigned short* xfT_cur = xfT0;  unsigned short* xfT_nxt = xfT1;
    unsigned short* Abig_cur = Abig0; unsigned short* Abig_nxt = Abig1;
    for (int l = 0; l < 3; ++l) {
        smm_k<<<dim3(8, NBT), 256, 0, stream>>>(Asb, Asqb, xfT_cur, Abig_cur);
        tmix_k<<<dim3(64, 8), 256, 0, stream>>>(Abig_cur,
                                                GbigT + (size_t)l * 8 * FF * KT,
                                                xfT_nxt, Abig_nxt, (l < 2) ? 1 : 0);
        unsigned short* tt = xfT_cur;  xfT_cur = xfT_nxt;  xfT_nxt = tt;
        unsigned short* tb = Abig_cur; Abig_cur = Abig_nxt; Abig_nxt = tb;
    }
    zredlin2_k<<<dim3(32, 8), 256, 0, stream>>>(Abig_cur, W2, b2, merge, out);
}

// Round 17
// 195.476 us; speedup vs baseline: 1.1679x; 1.1679x over previous
//
#include <hip/hip_runtime.h>

// B=8, T=8, S=500 (padded 512), F_IN=32, F=F_OUT=64, K=3, L=3
#define BB 8
#define TT 8
#define SS 500
#define SP 512
#define FIN 32
#define FF 64
#define NBT 64
#define KT 1536        // 24 * 64 : tmix GEMM K  (k = t'*192 + b'*64 + j)
#define LROW_S 136     // smm LDS row stride in shorts (BK=128 + 8 pad)
#define LROW_T 264     // tmix LDS row stride in shorts (BK=256 + 8 pad)

typedef short bf16x8 __attribute__((ext_vector_type(8)));
typedef float floatx4 __attribute__((ext_vector_type(4)));

__device__ __forceinline__ unsigned f2bf(float x) {
    unsigned u = __builtin_bit_cast(unsigned, x);
    return (u + 0x7FFFu + ((u >> 16) & 1u)) >> 16;   // RNE bf16 in low 16
}
__device__ __forceinline__ float bf2f(unsigned short h) {
    unsigned u = ((unsigned)h) << 16;
    return __builtin_bit_cast(float, u);
}

__device__ __forceinline__ void ctab(int m, float s0, float s1, float s2, float s3,
                                     float& c0, float& c1, float& c2) {
    c0 = 0.f; c1 = 0.f; c2 = 0.f;
    switch (m) {
        case 0: c0 = 1.f; c1 = s0; c2 = s0 * s0; break;
        case 1: c1 = s1; c2 = 2.f * s0 * s1; break;
        case 2: c2 = s1 * s1; break;
        case 3: c1 = s2; c2 = 2.f * s0 * s2; break;
        case 4: c1 = s3; c2 = 2.f * (s0 * s3 + s1 * s2); break;
        case 5: c2 = 2.f * s1 * s3; break;
        case 6: c2 = s2 * s2; break;
        case 7: c2 = 2.f * s2 * s3; break;
        case 8: c2 = s3 * s3; break;
    }
}

// ---------------------------------------------------------------------------
// setup_k: blocks [0,512): lin1; blocks [512,...): Asb/AsbT + GbigT
// ---------------------------------------------------------------------------
__global__ __launch_bounds__(256) void setup_k(const float* __restrict__ x,
                                               const float* __restrict__ W1,
                                               const float* __restrict__ b1,
                                               const float* __restrict__ As,
                                               const float* __restrict__ At,
                                               const float* __restrict__ sc,
                                               const float* __restrict__ H,
                                               unsigned short* __restrict__ Asb,
                                               unsigned short* __restrict__ AsbT,
                                               unsigned short* __restrict__ GbigT,
                                               unsigned short* __restrict__ xfT,
                                               unsigned short* __restrict__ Abig0) {
    int tid = threadIdx.x;
    if (blockIdx.x < 512) {
        // ---- lin1 path
        __shared__ float Xs[64][FIN + 1];
        __shared__ float Wl[FIN][FF];
        __shared__ float Ot[64][FF + 1];
        __shared__ float bl[FF];
        int bt = blockIdx.x >> 3, s0 = (blockIdx.x & 7) * 64;
        int b = bt >> 3, t = bt & 7;

        for (int i = tid; i < FIN * FF; i += 256) { int f = i >> 5, j = i & 31; Wl[j][f] = W1[i]; }
        if (tid < FF) bl[tid] = b1[tid];
        const float* xb = x + (size_t)bt * SS * FIN;
        #pragma unroll
        for (int i = 0; i < 8; ++i) {
            int lin = i * 256 + tid; int r = lin >> 5, j = lin & 31;
            int s = s0 + r;
            Xs[r][j] = (s < SS) ? xb[(size_t)s * FIN + j] : 0.f;
        }
        __syncthreads();
        int f = tid & 63, sq = tid >> 6;
        for (int i = 0; i < 16; ++i) {
            int r = sq * 16 + i;
            float acc = bl[f];
            #pragma unroll
            for (int j = 0; j < FIN; ++j) acc += Xs[r][j] * Wl[j][f];
            Ot[r][f] = (s0 + r < SS) ? acc : 0.f;
        }
        __syncthreads();
        // Abig0 slot0 write (row-major)
        #pragma unroll
        for (int it = 0; it < 2; ++it) {
            int idx = it * 256 + tid;
            int row = idx >> 3, c = idx & 7;
            int4 w;
            unsigned short tmp[8];
            #pragma unroll
            for (int q = 0; q < 8; ++q) tmp[q] = (unsigned short)f2bf(Ot[row][c * 8 + q]);
            w.x = tmp[0] | (tmp[1] << 16); w.y = tmp[2] | (tmp[3] << 16);
            w.z = tmp[4] | (tmp[5] << 16); w.w = tmp[6] | (tmp[7] << 16);
            *(int4*)(Abig0 + (size_t)(b * SP + s0 + row) * KT + t * 192 + c * 8) = w;
        }
        // transposed write
        {
            int ff = tid >> 2, scol = (tid & 3) * 16;
            unsigned short tmp[16];
            #pragma unroll
            for (int i = 0; i < 16; ++i) tmp[i] = (unsigned short)f2bf(Ot[scol + i][ff]);
            unsigned short* dp = xfT + ((size_t)bt * FF + ff) * SP + s0 + scol;
            #pragma unroll
            for (int q = 0; q < 2; ++q) {
                int4 w;
                w.x = tmp[q*8+0] | (tmp[q*8+1] << 16); w.y = tmp[q*8+2] | (tmp[q*8+3] << 16);
                w.z = tmp[q*8+4] | (tmp[q*8+5] << 16); w.w = tmp[q*8+6] | (tmp[q*8+7] << 16);
                *(int4*)(dp + q * 8) = w;
            }
        }
        return;
    }
    // ---- prep path
    int idx = (blockIdx.x - 512) * 256 + tid;
    if (idx < 262144) {
        int s = idx >> 9, k = idx & 511;
        Asb[idx] = (s < SS && k < SS) ? (unsigned short)f2bf(As[(size_t)s * SS + k]) : 0;
    } else if (idx < 524288) {
        int r = idx - 262144;
        int j = r >> 9, k = r & 511;
        AsbT[r] = (j < SS && k < SS) ? (unsigned short)f2bf(As[(size_t)k * SS + j]) : 0;
    } else {
        int r = idx - 524288;                 // [0, 3*8*64*1536)
        if (r < 2359296) {
            int l = r / 786432;
            int r2 = r - l * 786432;
            int t = r2 / 98304;
            int r3 = r2 - t * 98304;
            int f = r3 / 1536;
            int k = r3 - f * 1536;            // 1536 not pow2 — subtract, not AND
            int seg = k >> 6, j = k & 63;
            int tp = seg / 3, bp = seg - tp * 3;

            float s0 = sc[0], s1 = sc[1], s2 = sc[2], s3 = sc[3];
            float w0 = (t == tp) ? 1.f : 0.f;
            float w1 = At[t * 8 + tp];
            float w2 = 0.f;
            #pragma unroll
            for (int kk = 0; kk < 8; ++kk) w2 += At[t * 8 + kk] * At[kk * 8 + tp];

            float a0, a1, a2, b0, b1, b2, d0, d1, d2;
            ctab(0 * 3 + bp, s0, s1, s2, s3, a0, a1, a2);
            ctab(1 * 3 + bp, s0, s1, s2, s3, b0, b1, b2);
            ctab(2 * 3 + bp, s0, s1, s2, s3, d0, d1, d2);
            float k0c = w0 * a0 + w1 * b0 + w2 * d0;
            float k1c = w0 * a1 + w1 * b1 + w2 * d1;
            float k2c = w0 * a2 + w1 * b2 + w2 * d2;

            float val = k0c * H[((size_t)(l * 3 + 0) * 64 + j) * 64 + f]
                      + k1c * H[((size_t)(l * 3 + 1) * 64 + j) * 64 + f]
                      + k2c * H[((size_t)(l * 3 + 2) * 64 + j) * 64 + f];
            GbigT[r] = (unsigned short)f2bf(val);
        }
    }
}

// ---------------------------------------------------------------------------
// prep2: Asqb = (As@As) bf16 [512][512]
// ---------------------------------------------------------------------------
__global__ __launch_bounds__(256) void prep2_k(const unsigned short* __restrict__ Asb,
                                               const unsigned short* __restrict__ AsbT,
                                               unsigned short* __restrict__ Asqb) {
    int tid = threadIdx.x;
    int wave = tid >> 6, lane = tid & 63;
    int l16 = lane & 15, quad = lane >> 4;
    int st = blockIdx.x, ct = blockIdx.y;

    const unsigned short* ap = Asb + (size_t)(st * 16 + l16) * SP + quad * 8;
    const unsigned short* bp = AsbT + (size_t)(ct * 64 + wave * 16 + l16) * SP + quad * 8;
    floatx4 acc = {};
    #pragma unroll 4
    for (int k0 = 0; k0 < SP; k0 += 32)
        acc = __builtin_amdgcn_mfma_f32_16x16x32_bf16(*(const bf16x8*)(ap + k0),
                                                      *(const bf16x8*)(bp + k0), acc, 0, 0, 0);
    int j = ct * 64 + wave * 16 + l16;
    int i0 = st * 16 + quad * 4;
    #pragma unroll
    for (int r = 0; r < 4; ++r)
        Asqb[(size_t)(i0 + r) * SP + j] = (unsigned short)f2bf(acc[r]);
}

// ---------------------------------------------------------------------------
// smm (BK=128, 4 k-steps): u1 = As.xf, u2 = As^2.xf -> Abig slots 1,2.
// grid (8 m-tiles, 64 bt). LDS 3 x 64 x 136 shorts = 52 KB.
// ---------------------------------------------------------------------------
__global__ __launch_bounds__(256) void smm_k(const unsigned short* __restrict__ Asb,
                                             const unsigned short* __restrict__ Asqb,
                                             const unsigned short* __restrict__ xfT,
                                             unsigned short* __restrict__ Abig) {
    __shared__ unsigned short A1[64 * LROW_S];
    __shared__ unsigned short A2[64 * LROW_S];
    __shared__ unsigned short Bt[64 * LROW_S];

    int tid = threadIdx.x;
    int wave = tid >> 6, lane = tid & 63;
    int l16 = lane & 15, quad = lane >> 4;
    int m0 = blockIdx.x * 64, bt = blockIdx.y;
    int b = bt >> 3, t = bt & 7;

    const unsigned short* a1g = Asb + (size_t)m0 * SP;
    const unsigned short* a2g = Asqb + (size_t)m0 * SP;
    const unsigned short* bg  = xfT + (size_t)bt * FF * SP;

    floatx4 acc1[4] = {}, acc2[4] = {};

    for (int k0 = 0; k0 < SP; k0 += 128) {
        __syncthreads();
        #pragma unroll
        for (int it = 0; it < 4; ++it) {
            int idx = it * 256 + tid;
            int row = idx >> 4, c = idx & 15;
            int4 v1 = *(const int4*)(a1g + (size_t)row * SP + k0 + c * 8);
            int4 v2 = *(const int4*)(a2g + (size_t)row * SP + k0 + c * 8);
            int4 vb = *(const int4*)(bg  + (size_t)row * SP + k0 + c * 8);
            *(int4*)&A1[row * LROW_S + c * 8] = v1;
            *(int4*)&A2[row * LROW_S + c * 8] = v2;
            *(int4*)&Bt[row * LROW_S + c * 8] = vb;
        }
        __syncthreads();
        #pragma unroll
        for (int ks = 0; ks < 4; ++ks) {
            bf16x8 af1 = *(const bf16x8*)&A1[(wave * 16 + l16) * LROW_S + ks * 32 + quad * 8];
            bf16x8 af2 = *(const bf16x8*)&A2[(wave * 16 + l16) * LROW_S + ks * 32 + quad * 8];
            #pragma unroll
            for (int nt = 0; nt < 4; ++nt) {
                bf16x8 bf = *(const bf16x8*)&Bt[(nt * 16 + l16) * LROW_S + ks * 32 + quad * 8];
                acc1[nt] = __builtin_amdgcn_mfma_f32_16x16x32_bf16(af1, bf, acc1[nt], 0, 0, 0);
                acc2[nt] = __builtin_amdgcn_mfma_f32_16x16x32_bf16(af2, bf, acc2[nt], 0, 0, 0);
            }
        }
    }

    // epilogue: repack to row-major via LDS, write Abig slots 1 and 2
    __syncthreads();
    #pragma unroll
    for (int nt = 0; nt < 4; ++nt)
        #pragma unroll
        for (int r = 0; r < 4; ++r) {
            A1[(wave * 16 + quad * 4 + r) * LROW_S + nt * 16 + l16] = (unsigned short)f2bf(acc1[nt][r]);
            A2[(wave * 16 + quad * 4 + r) * LROW_S + nt * 16 + l16] = (unsigned short)f2bf(acc2[nt][r]);
        }
    __syncthreads();
    int row = wave * 16 + (lane >> 2);
    int c2 = (lane & 3) * 2;
    #pragma unroll
    for (int q = 0; q < 2; ++q) {
        int c = c2 + q;
        int4 v1 = *(const int4*)&A1[row * LROW_S + c * 8];
        int4 v2 = *(const int4*)&A2[row * LROW_S + c * 8];
        size_t base = (size_t)(b * SP + m0 + row) * KT + t * 192;
        *(int4*)(Abig + base + 64 + c * 8)  = v1;
        *(int4*)(Abig + base + 128 + c * 8) = v2;
    }
}

// ---------------------------------------------------------------------------
// tmix (BK=256, 6 k-steps, 2x2 wave tiles): grid (64 m-tiles, 8 t).
// C[(b,s)][(t,f)] = tanh( Abig @ GbigT_l[t]^T ). LDS 2 x 64 x 264 shorts.
// Writes xfT_next (if wflag) + Abig_next slot0.
// ---------------------------------------------------------------------------
__global__ __launch_bounds__(256) void tmix_k(const unsigned short* __restrict__ Abig,
                                              const unsigned short* __restrict__ GbigT_l,
                                              unsigned short* __restrict__ xfT_out,
                                              unsigned short* __restrict__ Abig_out,
                                              int wflag) {
    __shared__ unsigned short At_[64 * LROW_T];
    __shared__ unsigned short Bt_[64 * LROW_T];

    int tid = threadIdx.x;
    int wave = tid >> 6, lane = tid & 63;
    int l16 = lane & 15, quad = lane >> 4;
    int mi = wave & 1, ni = wave >> 1;     // 2x2 wave grid over 64x64 tile
    int m0 = blockIdx.x * 64, t = blockIdx.y;
    int b = m0 >> 9, s0 = m0 & 511;

    const unsigned short* ag = Abig + (size_t)m0 * KT;
    const unsigned short* bg = GbigT_l + (size_t)t * FF * KT;

    floatx4 acc[2][2] = {};

    for (int kk = 0; kk < 6; ++kk) {
        __syncthreads();
        #pragma unroll
        for (int it = 0; it < 8; ++it) {
            int idx = it * 256 + tid;
            int row = idx >> 5, c = idx & 31;
            int4 va = *(const int4*)(ag + (size_t)row * KT + kk * 256 + c * 8);
            int4 vb = *(const int4*)(bg + (size_t)row * KT + kk * 256 + c * 8);
            *(int4*)&At_[row * LROW_T + c * 8] = va;
            *(int4*)&Bt_[row * LROW_T + c * 8] = vb;
        }
        __syncthreads();
        #pragma unroll
        for (int ks = 0; ks < 8; ++ks) {
            bf16x8 af[2], bf[2];
            #pragma unroll
            for (int mt = 0; mt < 2; ++mt)
                af[mt] = *(const bf16x8*)&At_[(mi * 32 + mt * 16 + l16) * LROW_T + ks * 32 + quad * 8];
            #pragma unroll
            for (int nt = 0; nt < 2; ++nt)
                bf[nt] = *(const bf16x8*)&Bt_[(ni * 32 + nt * 16 + l16) * LROW_T + ks * 32 + quad * 8];
            #pragma unroll
            for (int mt = 0; mt < 2; ++mt)
                #pragma unroll
                for (int nt = 0; nt < 2; ++nt)
                    acc[mt][nt] = __builtin_amdgcn_mfma_f32_16x16x32_bf16(af[mt], bf[nt], acc[mt][nt], 0, 0, 0);
        }
    }

    // tanh
    #pragma unroll
    for (int mt = 0; mt < 2; ++mt)
        #pragma unroll
        for (int nt = 0; nt < 2; ++nt)
            #pragma unroll
            for (int r = 0; r < 4; ++r) acc[mt][nt][r] = tanhf(acc[mt][nt][r]);

    int bt = b * 8 + t;

    // xfT write straight from registers (skipped on last layer)
    if (wflag) {
        #pragma unroll
        for (int mt = 0; mt < 2; ++mt) {
            int sbase = s0 + mi * 32 + mt * 16 + quad * 4;
            #pragma unroll
            for (int nt = 0; nt < 2; ++nt) {
                int f = ni * 32 + nt * 16 + l16;
                int2 w;
                w.x = (int)(f2bf(acc[mt][nt][0]) | (f2bf(acc[mt][nt][1]) << 16));
                w.y = (int)(f2bf(acc[mt][nt][2]) | (f2bf(acc[mt][nt][3]) << 16));
                *(int2*)(xfT_out + ((size_t)bt * FF + f) * SP + sbase) = w;
            }
        }
    }

    // Abig_out slot0 via LDS repack (coalesced int4 rows)
    __syncthreads();
    #pragma unroll
    for (int mt = 0; mt < 2; ++mt)
        #pragma unroll
        for (int nt = 0; nt < 2; ++nt)
            #pragma unroll
            for (int r = 0; r < 4; ++r)
                At_[(mi * 32 + mt * 16 + quad * 4 + r) * LROW_T + ni * 32 + nt * 16 + l16] =
                    (unsigned short)f2bf(acc[mt][nt][r]);
    __syncthreads();
    {
        int row = wave * 16 + (lane >> 2);
        int c2 = (lane & 3) * 2;
        #pragma unroll
        for (int q = 0; q < 2; ++q) {
            int c = c2 + q;
            int4 v = *(const int4*)&At_[row * LROW_T + c * 8];
            *(int4*)(Abig_out + (size_t)(m0 + row) * KT + t * 192 + c * 8) = v;
        }
    }
}

// ---------------------------------------------------------------------------
// zredlin2: out[b,s,f] = b2[f]*sum(m) + z @ W2^T, z from Abig slot0.
// grid (32 s-tiles of 16, 8 b)
// ---------------------------------------------------------------------------
__global__ __launch_bounds__(256) void zredlin2_k(const unsigned short* __restrict__ Abig,
                                                  const float* __restrict__ W2,
                                                  const float* __restrict__ b2,
                                                  const float* __restrict__ merge,
                                                  float* __restrict__ out) {
    __shared__ float Wl[FF][FF + 1];
    __shared__ float zt[16][FF + 1];
    __shared__ float ml[TT];
    int tid = threadIdx.x;
    int b = blockIdx.y, s0 = blockIdx.x * 16;

    for (int i = tid; i < FF * FF; i += 256) { int f = i >> 6, j = i & 63; Wl[j][f] = W2[i]; }
    if (tid < TT) ml[tid] = merge[tid];
    __syncthreads();

    float m[TT];
    #pragma unroll
    for (int t = 0; t < TT; ++t) m[t] = ml[t];
    float msum = 0.f;
    #pragma unroll
    for (int t = 0; t < TT; ++t) msum += m[t];

    #pragma unroll
    for (int p = 0; p < 4; ++p) {
        int lin = p * 256 + tid;
        int sl = lin >> 6, f = lin & 63;
        int s = s0 + sl;
        float acc = 0.f;
        if (s < SS) {
            #pragma unroll
            for (int t = 0; t < TT; ++t)
                acc += m[t] * bf2f(Abig[(size_t)(b * SP + s) * KT + t * 192 + f]);
        }
        zt[sl][f] = acc;
    }
    __syncthreads();

    int f = tid & 63, sq = tid >> 6;
    #pragma unroll
    for (int i = 0; i < 4; ++i) {
        int sl = sq * 4 + i;
        int s = s0 + sl;
        if (s < SS) {
            float acc = b2[f] * msum;
            #pragma unroll
            for (int j = 0; j < FF; ++j) acc += zt[sl][j] * Wl[j][f];
            out[((size_t)b * SS + s) * FF + f] = acc;
        }
    }
}

// ---------------------------------------------------------------------------
extern "C" void kernel_launch(void* const* d_in, const int* in_sizes, int n_in,
                              void* d_out, int out_size, void* d_ws, size_t ws_size,
                              hipStream_t stream) {
    const float* x     = (const float*)d_in[0];
    const float* At    = (const float*)d_in[1];
    const float* As    = (const float*)d_in[2];
    const float* sc    = (const float*)d_in[3];
    const float* H     = (const float*)d_in[4];
    const float* W1    = (const float*)d_in[5];
    const float* b1    = (const float*)d_in[6];
    const float* W2    = (const float*)d_in[7];
    const float* b2    = (const float*)d_in[8];
    const float* merge = (const float*)d_in[9];
    float* out = (float*)d_out;

    char* ws = (char*)d_ws;
    unsigned short* Asb   = (unsigned short*)(ws + 0);          // 524288
    unsigned short* AsbT  = (unsigned short*)(ws + 524288);     // 524288
    unsigned short* Asqb  = (unsigned short*)(ws + 1048576);    // 524288
    unsigned short* GbigT = (unsigned short*)(ws + 1572864);    // 4718592
    unsigned short* xfT0  = (unsigned short*)(ws + 6291456);    // 4194304
    unsigned short* xfT1  = (unsigned short*)(ws + 10485760);   // 4194304
    unsigned short* Abig0 = (unsigned short*)(ws + 14680064);   // 12582912
    unsigned short* Abig1 = (unsigned short*)(ws + 27262976);   // 12582912

    setup_k<<<11776, 256, 0, stream>>>(x, W1, b1, As, At, sc, H,
                                       Asb, AsbT, GbigT, xfT0, Abig0);
    prep2_k<<<dim3(32, 8), 256, 0, stream>>>(Asb, AsbT, Asqb);

    unsigned short* xfT_cur = xfT0;  unsigned short* xfT_nxt = xfT1;
    unsigned short* Abig_cur = Abig0; unsigned short* Abig_nxt = Abig1;
    for (int l = 0; l < 3; ++l) {
        smm_k<<<dim3(8, NBT), 256, 0, stream>>>(Asb, Asqb, xfT_cur, Abig_cur);
        tmix_k<<<dim3(64, 8), 256, 0, stream>>>(Abig_cur,
                                                GbigT + (size_t)l * 8 * FF * KT,
                                                xfT_nxt, Abig_nxt, (l < 2) ? 1 : 0);
        unsigned short* tt = xfT_cur;  xfT_cur = xfT_nxt;  xfT_nxt = tt;
        unsigned short* tb = Abig_cur; Abig_cur = Abig_nxt; Abig_nxt = tb;
    }
    zredlin2_k<<<dim3(32, 8), 256, 0, stream>>>(Abig_cur, W2, b2, merge, out);
}